// Round 1
// 212.970 us; speedup vs baseline: 1.0170x; 1.0170x over previous
//
#include <hip/hip_runtime.h>
#include <hip/hip_bf16.h>
#include <stdint.h>

namespace {
constexpr int kBatch = 256;
constexpr int kNoise = 128;
constexpr int kIn    = 512;
constexpr int kOut   = 512;
constexpr int kXCols = kNoise + kIn;        // 640
constexpr int kPCols = kIn * kOut + kOut;   // 262656 (W row stride)
constexpr int kOTile = 32;
constexpr int kITile = 16;
constexpr int kSplits = kIn / kITile;       // 32 partial slabs
constexpr int kWStride = 68;                // LDS col stride in dwords (64 kp + 4 pad)
constexpr int kFeatsStride = 260;
constexpr int kSlab = kBatch * kOut + 64;   // partial slab stride, padded +256B to break
                                            // 512KB power-of-2 channel aliasing in reduce
}

typedef __bf16 bf16x8 __attribute__((ext_vector_type(8)));
typedef float  f32x4  __attribute__((ext_vector_type(4)));
typedef unsigned int u32x4 __attribute__((ext_vector_type(4)));

__device__ inline unsigned int pack_bf16x2(float lo, float hi) {
    unsigned int a = (unsigned int)__builtin_bit_cast(unsigned short, (__bf16)lo);
    unsigned int b = (unsigned int)__builtin_bit_cast(unsigned short, (__bf16)hi);
    return a | (b << 16);
}

// Barrier draining LDS ops only (lgkmcnt(0)); vmcnt untouched so global
// prefetch loads stay in flight across it.
__device__ inline void wg_barrier_lds() {
    __asm__ volatile("" ::: "memory");
    __builtin_amdgcn_s_waitcnt(0xC07F);   // lgkmcnt(0), vmcnt/expcnt = no-wait
    __builtin_amdgcn_s_barrier();
    __asm__ volatile("" ::: "memory");
}

// Stage 1: part[split][b][o] = sum_{i in split} feats[b,i]*(noise@W + bvec)[b, i*512+o]
//          (+ bias-term pass folded into split 0)
// Grid (16 o-tiles, 32 i-splits) = 512 WGs x 512 thr (8 waves).
// Each wave owns 32 batch rows (2 A-frag sets, 16 MFMA/pass): halves the
// per-W-byte LDS read amplification (8 waves re-read tile instead of 16)
// so LDS-read time (~1600 cyc/CU/pass) drops well under HBM (~3200 cyc).
// 128-VGPR tier (launch_bounds 512,4) -> 2 WG/CU = 16 waves/CU, with register
// headroom for depth-3 f32x4 (16B/lane) W prefetch: 96B/thread in flight.
__global__ __launch_bounds__(512, 4)
void hyper_gemm_kernel(const float* __restrict__ x,
                       const float* __restrict__ W,
                       const float* __restrict__ bvec,
                       float* __restrict__ part)
{
    const int tid  = threadIdx.x;
    const int lane = tid & 63;
    const int wave = tid >> 6;     // 0..7, owns batch rows [wave*32, wave*32+32)
    const int q    = lane >> 4;
    const int l16  = lane & 15;

    const int o0 = blockIdx.x * kOTile;
    const int i0 = blockIdx.y * kITile;

    // W staging role: thread covers rows {2u, 2u+1}, cols {c4..c4+3} (f32x4 loads)
    const int u  = tid >> 3;            // 0..63 (k-pair index)
    const int c4 = (tid & 7) * 4;       // 0,4,..,28

    __shared__ unsigned int wtile[2][kOTile * kWStride];   // dbuf bf16-pair tile [col][kp]
    __shared__ float feats_lds[kITile * kFeatsStride];     // [i][b] transposed
    __shared__ float bv_lds[(kITile + 1) * kOTile];        // [pass][col]

    const int nPass = (blockIdx.y == 0) ? (kITile + 1) : kITile;

    auto pass_cbase = [&](int p) -> size_t {
        return (p == kITile) ? (size_t)(kIn * kOut) : (size_t)(i0 + p) * kOut;
    };
    auto wrow = [&](int p) -> const float* {
        return W + (size_t)(2 * u) * kPCols + pass_cbase(p) + o0 + c4;
    };

    // ---- prologue: issue depth-3 W prefetch FIRST (HBM-latency loads) ----
    f32x4 pA0, pA1, pB0, pB1, pC0, pC1;   // rows {2u,2u+1} x cols {c4..c4+3}
    { const float* wp = wrow(0); pA0 = *(const f32x4*)wp; pA1 = *(const f32x4*)(wp + kPCols); }
    { const float* wp = wrow(1); pB0 = *(const f32x4*)wp; pB1 = *(const f32x4*)(wp + kPCols); }
    { const float* wp = wrow(2); pC0 = *(const f32x4*)wp; pC1 = *(const f32x4*)(wp + kPCols); }

    // bvec -> LDS
    for (int idx = tid; idx < (kITile + 1) * kOTile; idx += 512) {
        const int p = idx >> 5, c = idx & 31;
        const size_t cb = (p == kITile) ? (size_t)(kIn * kOut) : (size_t)(i0 + p) * kOut;
        bv_lds[idx] = bvec[cb + o0 + c];
    }

    // feats[b][i0+i] -> feats_lds[i][b]
    {
        const int i    = tid & 15;
        const int brow = tid >> 4;      // 0..31
        #pragma unroll
        for (int rep = 0; rep < 8; ++rep) {
            const int b = brow + rep * 32;
            feats_lds[i * kFeatsStride + b] = x[b * kXCols + kNoise + i0 + i];
        }
    }

    // Noise A-fragments (resident, 32 VGPRs). A[m=lane&15][k=q*8+j], k_global=32*s+k.
    bf16x8 afrag[2][4];
    #pragma unroll
    for (int rt = 0; rt < 2; ++rt) {
        const float* xr = x + (size_t)(wave * 32 + rt * 16 + l16) * kXCols;
        #pragma unroll
        for (int s = 0; s < 4; ++s) {
            const float* p = xr + s * 32 + q * 8;
            f32x4 u0 = *(const f32x4*)(p);
            f32x4 u1 = *(const f32x4*)(p + 4);
            bf16x8 a;
            a[0] = (__bf16)u0[0]; a[1] = (__bf16)u0[1];
            a[2] = (__bf16)u0[2]; a[3] = (__bf16)u0[3];
            a[4] = (__bf16)u1[0]; a[5] = (__bf16)u1[1];
            a[6] = (__bf16)u1[2]; a[7] = (__bf16)u1[3];
            afrag[rt][s] = a;
        }
    }

    float oacc[2][2][4];   // [rt][nt][r]; b = wave*32+rt*16+q*4+r, o = o0+nt*16+l16
    #pragma unroll
    for (int rt = 0; rt < 2; ++rt)
        #pragma unroll
        for (int nt = 0; nt < 2; ++nt)
            #pragma unroll
            for (int r = 0; r < 4; ++r) oacc[rt][nt][r] = 0.f;

    __syncthreads();   // feats + bvec staged

    // ---- pipelined i-loop: 1 barrier/pass, steady-state vmcnt never drains ----
    for (int ip = 0; ip < nPass; ++ip) {
        // pack pass-ip regs (compiler waits only the oldest pair of loads)
        unsigned int pk0 = pack_bf16x2(pA0[0], pA1[0]);
        unsigned int pk1 = pack_bf16x2(pA0[1], pA1[1]);
        unsigned int pk2 = pack_bf16x2(pA0[2], pA1[2]);
        unsigned int pk3 = pack_bf16x2(pA0[3], pA1[3]);

        unsigned int* wt = &wtile[ip & 1][0];
        wt[(c4 + 0) * kWStride + u] = pk0;
        wt[(c4 + 1) * kWStride + u] = pk1;
        wt[(c4 + 2) * kWStride + u] = pk2;
        wt[(c4 + 3) * kWStride + u] = pk3;

        pA0 = pB0; pA1 = pB1; pB0 = pC0; pB1 = pC1;
        if (ip + 3 < nPass) {
            const float* wp = wrow(ip + 3);
            pC0 = *(const f32x4*)wp; pC1 = *(const f32x4*)(wp + kPCols);
        }

        wg_barrier_lds();   // tile[ip&1] visible; prior-buffer readers done

        // GEMM: acc[b,col] = noise @ W[:, cbase+o0+col]
        f32x4 acc[2][2];
        const f32x4 zero = {0.f, 0.f, 0.f, 0.f};
        acc[0][0] = zero; acc[0][1] = zero; acc[1][0] = zero; acc[1][1] = zero;

        #pragma unroll
        for (int s = 0; s < 4; ++s) {
            #pragma unroll
            for (int nt = 0; nt < 2; ++nt) {
                // B layout [k=q*8+j][col=l16]: 4 consecutive uints = 8 bf16 (k asc)
                u32x4 raw = *(const u32x4*)&wt[(nt * 16 + l16) * kWStride + s * 16 + q * 4];
                bf16x8 bfrag = __builtin_bit_cast(bf16x8, raw);
                acc[0][nt] = __builtin_amdgcn_mfma_f32_16x16x32_bf16(
                    afrag[0][s], bfrag, acc[0][nt], 0, 0, 0);
                acc[1][nt] = __builtin_amdgcn_mfma_f32_16x16x32_bf16(
                    afrag[1][s], bfrag, acc[1][nt], 0, 0, 0);
            }
        }

        // epilogue (fp32): oacc += feats[b,i] * (acc + bvec[c]); bias pass scale=1
        const float bv0 = bv_lds[ip * kOTile + l16];
        const float bv1 = bv_lds[ip * kOTile + 16 + l16];

        if (ip < kITile) {
            // C/D layout: col = lane&15, row = q*4 + reg
            #pragma unroll
            for (int rt = 0; rt < 2; ++rt) {
                const f32x4 f4 = *(const f32x4*)&feats_lds[ip * kFeatsStride
                                        + wave * 32 + rt * 16 + q * 4];
                #pragma unroll
                for (int r = 0; r < 4; ++r) {
                    oacc[rt][0][r] += f4[r] * (acc[rt][0][r] + bv0);
                    oacc[rt][1][r] += f4[r] * (acc[rt][1][r] + bv1);
                }
            }
        } else {
            #pragma unroll
            for (int rt = 0; rt < 2; ++rt)
                #pragma unroll
                for (int r = 0; r < 4; ++r) {
                    oacc[rt][0][r] += acc[rt][0][r] + bv0;
                    oacc[rt][1][r] += acc[rt][1][r] + bv1;
                }
        }
    }

    // ---- stream partials (no atomics) ----
    float* pp = part + (size_t)blockIdx.y * kSlab;
    #pragma unroll
    for (int rt = 0; rt < 2; ++rt)
        #pragma unroll
        for (int nt = 0; nt < 2; ++nt) {
            const int o = o0 + nt * 16 + l16;
            #pragma unroll
            for (int r = 0; r < 4; ++r) {
                const int b = wave * 32 + rt * 16 + q * 4 + r;
                pp[(size_t)b * kOut + o] = oacc[rt][nt][r];
            }
        }
}

// Stage 2: out = sum over 32 slabs (16.8 MB, L2/L3-resident).
// 256 WGs x 128 thr -> one WG per CU, padded slab stride (kSlab).
__global__ __launch_bounds__(128)
void reduce_kernel(const float* __restrict__ part, float* __restrict__ out)
{
    const size_t idx4 = ((size_t)blockIdx.x * 128 + threadIdx.x) * 4;
    f32x4 acc = *(const f32x4*)(part + idx4);
    #pragma unroll
    for (int s = 1; s < kSplits; ++s)
        acc += *(const f32x4*)(part + (size_t)s * kSlab + idx4);
    *(f32x4*)(out + idx4) = acc;
}

extern "C" void kernel_launch(void* const* d_in, const int* in_sizes, int n_in,
                              void* d_out, int out_size, void* d_ws, size_t ws_size,
                              hipStream_t stream) {
    const float* x  = (const float*)d_in[0];
    const float* W  = (const float*)d_in[1];
    const float* bv = (const float*)d_in[2];
    float* out  = (float*)d_out;
    float* part = (float*)d_ws;   // 32 * kSlab * 4 B = 16.8 MB

    dim3 grid(kOut / kOTile, kSplits);  // (16, 32) = 512 WGs of 512 threads
    hyper_gemm_kernel<<<grid, 512, 0, stream>>>(x, W, bv, part);

    const int n4 = kBatch * kOut / 4;   // 32768 f32x4 outputs
    reduce_kernel<<<n4 / 128, 128, 0, stream>>>(part, out);
}